// Round 8
// baseline (435.297 us; speedup 1.0000x reference)
//
#include <hip/hip_runtime.h>

typedef unsigned short u16;
typedef unsigned int   u32;
typedef __attribute__((ext_vector_type(4))) float f32x4;
typedef __attribute__((ext_vector_type(4))) u32   u32x4;
typedef __attribute__((ext_vector_type(4))) int   i32x4;
typedef __attribute__((ext_vector_type(8))) __bf16 bf16x8;

constexpr int NV   = 50000;   // vertices
constexpr int NE   = 25000;   // hyperedges
constexpr int NNZp = 400000;  // incidence pairs
constexpr int D    = 512;     // d_in == d_out
constexpr int MP2  = 25088;   // NE padded to 128 (196*128) -- GEMM rows
constexpr int NBE  = 25;      // scan blocks for E (1024 elems each)
constexpr int NBV  = 49;      // scan blocks for V
constexpr int BPS1 = 391;     // stage1 blocks per slice: ceil(NE/64)
constexpr int BPS2 = 1563;    // stage2 blocks per slice: ceil(NV/32)

static __device__ __forceinline__ u16 f2bf(float f) {
  u32 u = __float_as_uint(f);
  u32 r = (u + 0x7fffu + ((u >> 16) & 1u)) >> 16;  // RNE
  return (u16)r;
}
static __device__ __forceinline__ u32 pk2(float a, float b) {
  return (u32)f2bf(a) | ((u32)f2bf(b) << 16);
}

static __device__ __forceinline__ void gload_lds16(const u16* g, u16* l) {
  // async global->LDS, 16B per lane; LDS dest = wave-uniform base + lane*16
  __builtin_amdgcn_global_load_lds(
      (const __attribute__((address_space(1))) u32*)g,
      (__attribute__((address_space(3))) u32*)l, 16, 0, 0);
}

// ---------------- zero counters + degree histograms ----------------
__global__ void zero_kernel(int* cntE, int* cntV, int* dhistE, int* dhistV) {
  int i = blockIdx.x * 256 + threadIdx.x;
  if (i < NE) cntE[i] = 0;
  if (i < NV) cntV[i] = 0;
  if (i < 64) { dhistE[i] = 0; dhistV[i] = 0; }
}

// ---------------- histogram of incidence pairs ----------------
__global__ void hist_kernel(const int* __restrict__ vidx, const int* __restrict__ eidx,
                            int* cntE, int* cntV) {
  int i = blockIdx.x * 256 + threadIdx.x;
  if (i < NNZp) {
    atomicAdd(&cntE[eidx[i]], 1);
    atomicAdd(&cntV[vidx[i]], 1);
  }
}

// ---------------- scan pass 1 + fused degree histogram -------------------------------
// Per-block (1024 elems) local exclusive scan of cnt -> off; also accumulates the
// 64-bucket degree histogram (LDS-aggregated) in the same pass over cnt.
__global__ __launch_bounds__(256) void scan1_kernel(
    const int* __restrict__ cntE, const int* __restrict__ cntV,
    int* offE, int* offV, int* blkSum, int* dhistE, int* dhistV) {
  const bool isE = blockIdx.x < NBE;
  const int* cnt = isE ? cntE : cntV;
  int* off = isE ? offE : offV;
  int* dhist = isE ? dhistE : dhistV;
  const int len = isE ? NE : NV;
  const int t = threadIdx.x;
  const int base = (isE ? blockIdx.x : blockIdx.x - NBE) * 1024 + t * 4;
  int4 c = {0, 0, 0, 0};
  if (base + 4 <= len) c = *(const int4*)(cnt + base);
  else {
    if (base + 0 < len) c.x = cnt[base + 0];
    if (base + 1 < len) c.y = cnt[base + 1];
    if (base + 2 < len) c.z = cnt[base + 2];
    if (base + 3 < len) c.w = cnt[base + 3];
  }
  int s = c.x + c.y + c.z + c.w;
  __shared__ int sm[256];
  __shared__ int lh[64];
  if (t < 64) lh[t] = 0;
  sm[t] = s;
  __syncthreads();
  // fused degree histogram (lh zeroed above barrier)
  if (base + 0 < len) atomicAdd(&lh[min(c.x, 63)], 1);
  if (base + 1 < len) atomicAdd(&lh[min(c.y, 63)], 1);
  if (base + 2 < len) atomicAdd(&lh[min(c.z, 63)], 1);
  if (base + 3 < len) atomicAdd(&lh[min(c.w, 63)], 1);
  for (int d = 1; d < 256; d <<= 1) {
    int u = (t >= d) ? sm[t - d] : 0;
    __syncthreads();
    sm[t] += u;
    __syncthreads();
  }
  int ex = sm[t] - s;  // exclusive prefix within block
  int4 o;
  o.x = ex; o.y = o.x + c.x; o.z = o.y + c.y; o.w = o.z + c.z;
  if (base + 4 <= len) *(int4*)(off + base) = o;
  else {
    if (base + 0 < len) off[base + 0] = o.x;
    if (base + 1 < len) off[base + 1] = o.y;
    if (base + 2 < len) off[base + 2] = o.z;
    if (base + 3 < len) off[base + 3] = o.w;
  }
  if (t == 255) blkSum[blockIdx.x] = sm[255];
  // flush histogram (scan loop's last barrier ordered all lh atomics)
  if (t < 64 && lh[t]) atomicAdd(&dhist[t], lh[t]);
}

// ---------------- scan pass 2: wave-scan blkSums + degree hists (exclusive) ----------
__global__ void scan2_kernel(int* blkSum, const int* __restrict__ dhistE,
                             const int* __restrict__ dhistV, int* dcurE, int* dcurV) {
  int wv = threadIdx.x >> 6, lane = threadIdx.x & 63;
  const int* s; int* d; int len;
  if (wv == 0)      { s = blkSum;       d = blkSum;       len = NBE; }
  else if (wv == 1) { s = blkSum + NBE; d = blkSum + NBE; len = NBV; }
  else if (wv == 2) { s = dhistE;       d = dcurE;        len = 64;  }
  else              { s = dhistV;       d = dcurV;        len = 64;  }
  int v = (lane < len) ? s[lane] : 0;
  int incl = v;
#pragma unroll
  for (int dd = 1; dd < 64; dd <<= 1) {
    int u = __shfl_up(incl, dd, 64);
    if (lane >= dd) incl += u;
  }
  if (lane < len) d[lane] = incl - v;
}

// ---------------- scan pass 3 + fused counting-sort by degree ------------------------
// Adds block prefixes -> final off/cur, then bucket-ranks each segment by degree
// (two-phase LDS+global) and writes packed metadata:
// sE_meta[r] = {edge_id, off, cnt, 0}; sV_meta[r] = {vert_id, off, cnt, bits(degV)}.
__global__ __launch_bounds__(256) void scan3_kernel(
    int* offE, int* offV, int* curE, int* curV, const int* __restrict__ blkSum,
    const int* __restrict__ cntE, const int* __restrict__ cntV,
    const float* __restrict__ degV, int* dcurE, int* dcurV,
    i32x4* sE_meta, i32x4* sV_meta) {
  const bool isE = blockIdx.x < NBE;
  int* off = isE ? offE : offV;
  int* cur = isE ? curE : curV;
  const int* cnt = isE ? cntE : cntV;
  int* dcur = isE ? dcurE : dcurV;
  i32x4* meta = isE ? sE_meta : sV_meta;
  const int len = isE ? NE : NV;
  const int pref = blkSum[blockIdx.x];
  const int t = threadIdx.x;
  const int base = (isE ? blockIdx.x : blockIdx.x - NBE) * 1024 + t * 4;
  __shared__ int lh[64], lb[64];
  if (t < 64) lh[t] = 0;
  __syncthreads();
  int os[4] = {}, cs[4] = {};
  bool val[4] = {};
  if (base + 4 <= len) {
    int4 o = *(int4*)(off + base);
    int4 c = *(const int4*)(cnt + base);
    os[0] = o.x + pref; os[1] = o.y + pref; os[2] = o.z + pref; os[3] = o.w + pref;
    cs[0] = c.x; cs[1] = c.y; cs[2] = c.z; cs[3] = c.w;
    val[0] = val[1] = val[2] = val[3] = true;
    int4 oo = {os[0], os[1], os[2], os[3]};
    *(int4*)(off + base) = oo;
    *(int4*)(cur + base) = oo;
  } else {
    for (int q = 0; q < 4; q++)
      if (base + q < len) {
        os[q] = off[base + q] + pref; cs[q] = cnt[base + q]; val[q] = true;
        off[base + q] = os[q]; cur[base + q] = os[q];
      }
  }
  int bq[4] = {}, rk[4] = {};
#pragma unroll
  for (int q = 0; q < 4; q++)
    if (val[q]) { bq[q] = min(cs[q], 63); rk[q] = atomicAdd(&lh[bq[q]], 1); }
  __syncthreads();
  if (t < 64) lb[t] = lh[t] ? atomicAdd(&dcur[t], lh[t]) : 0;
  __syncthreads();
#pragma unroll
  for (int q = 0; q < 4; q++)
    if (val[q]) {
      int id = base + q;
      int dw = 0;
      if (!isE) dw = __float_as_int(degV[id]);
      i32x4 m = { id, os[q], cs[q], dw };
      meta[lb[bq[q]] + rk[q]] = m;
    }
}

// ---------------- scatter pairs into CSR ----------------
__global__ void scatter_kernel(const int* __restrict__ vidx, const int* __restrict__ eidx,
                               int* curE, int* curV, int* csr_ev, int* csr_ve) {
  int i = blockIdx.x * 256 + threadIdx.x;
  if (i < NNZp) {
    int e = eidx[i], v = vidx[i];
    csr_ev[atomicAdd(&curE[e], 1)] = v;  // edge -> member vertices
    csr_ve[atomicAdd(&curV[v], 1)] = e;  // vertex -> incident edges
  }
}

// ---------------- fp32 -> bf16 convert -----------------------------------------------
// X -> Xb in SLICE-MAJOR layout [16][NV][32] (slice = 3.2 MB, fits one XCD's 4 MB L2).
// W -> Wb row-major. NT stores: outputs not re-read through this kernel's L2.
__global__ __launch_bounds__(256) void convert_kernel(
    const float* __restrict__ X, const float* __restrict__ W,
    u16* __restrict__ Xb, u16* __restrict__ Wb) {
  constexpr size_t NX = (size_t)NV * D;  // 25,600,000 (divisible by 8)
  size_t i = ((size_t)blockIdx.x * 256 + threadIdx.x) * 8;
  const float* src;
  u16* dst;
  if (i < NX) {
    int n = (int)(i >> 9);
    int col = (int)(i & 511);
    int t = col >> 5, w = col & 31;
    src = X + i;
    dst = Xb + (size_t)t * NV * 32 + (size_t)n * 32 + w;
  } else {
    src = W + (i - NX);
    dst = Wb + (i - NX);
  }
  f32x4 a = *(const f32x4*)src;
  f32x4 b = *(const f32x4*)(src + 4);
  u32x4 p = { pk2(a[0], a[1]), pk2(a[2], a[3]), pk2(b[0], b[1]), pk2(b[2], b[3]) };
  __builtin_nontemporal_store(p, (u32x4*)dst);
}

// ---------------- stage 1: vertex -> hyperedge ---------------------------------------
// Slice-pinned (16 x 32-col slices via bid&7 + phase), degree-SORTED ranks, CACHED
// coalesced idx loads shfl-broadcast, 16-DEEP independent gather windows (one idx-wait
// per 16 members). XeR written with NT stores (consumed later on other XCDs).
__global__ __launch_bounds__(256) void stage1_kernel(
    const u16* __restrict__ Xb, const i32x4* __restrict__ sE_meta,
    const int* __restrict__ csr_ev, u16* __restrict__ XeR) {
  const int wave = threadIdx.x >> 6;
  const int lane = threadIdx.x & 63;
  const int g    = lane >> 2;      // 0..15: segment slot
  const int c    = lane & 3;       // 4 lanes x 16B = 64B = 32 cols
  const int bid  = blockIdx.x;
  const int xcd  = bid & 7;
  const int tmp  = bid >> 3;                    // 0 .. 2*BPS1-1
  const int phase = (tmp >= BPS1) ? 1 : 0;
  const int eg    = tmp - phase * BPS1;
  const int t     = xcd + 8 * phase;            // slice 0..15
  const int rank  = eg * 64 + wave * 16 + g;
  const u16* base = Xb + (size_t)t * NV * 32;
  int e = 0, start = 0, cnt = 0;
  if (rank < NE) {
    i32x4 m = sE_meta[rank];
    e = m.x; start = m.y; cnt = m.z;
  }
  float acc[8] = {};
  int j0 = 0;
  for (; j0 + 16 <= cnt; j0 += 16) {            // full windows: no guards
    int ia = csr_ev[start + j0 + c];
    int ib = csr_ev[start + j0 + 4 + c];
    int ic = csr_ev[start + j0 + 8 + c];
    int id = csr_ev[start + j0 + 12 + c];
    u32x4 pk[16];
#pragma unroll
    for (int k = 0; k < 16; k++) {
      int src = (k < 4) ? ia : (k < 8) ? ib : (k < 12) ? ic : id;
      int v = __shfl(src, (lane & ~3) | (k & 3), 64);
      pk[k] = *(const u32x4*)(base + (size_t)v * 32 + c * 8);
    }
#pragma unroll
    for (int k = 0; k < 16; k++)
#pragma unroll
      for (int q = 0; q < 4; q++) {
        u32 u = pk[k][q];
        acc[2 * q]     += __uint_as_float(u << 16);
        acc[2 * q + 1] += __uint_as_float(u & 0xffff0000u);
      }
  }
  const int rem = cnt - j0;                     // 0..15, group-uniform
  if (rem) {
    int ia = csr_ev[start + j0 + c];            // <=60B overread: lands in-ws, safe
    int ib = csr_ev[start + j0 + 4 + c];
    int ic = csr_ev[start + j0 + 8 + c];
    int id = csr_ev[start + j0 + 12 + c];
    u32x4 pk[16];
#pragma unroll
    for (int k = 0; k < 16; k++) {
      if (k < rem) {
        int src = (k < 4) ? ia : (k < 8) ? ib : (k < 12) ? ic : id;
        int v = __shfl(src, (lane & ~3) | (k & 3), 64);
        pk[k] = *(const u32x4*)(base + (size_t)v * 32 + c * 8);
      }
    }
#pragma unroll
    for (int k = 0; k < 16; k++)
      if (k < rem)
#pragma unroll
        for (int q = 0; q < 4; q++) {
          u32 u = pk[k][q];
          acc[2 * q]     += __uint_as_float(u << 16);
          acc[2 * q + 1] += __uint_as_float(u & 0xffff0000u);
        }
  }
  if (rank < NE) {
    u32x4 o = { pk2(acc[0], acc[1]), pk2(acc[2], acc[3]),
                pk2(acc[4], acc[5]), pk2(acc[6], acc[7]) };
    __builtin_nontemporal_store(o, (u32x4*)(XeR + (size_t)e * D + t * 32 + c * 8));
  }
}

// ---------------- GEMM: Xe2 = (XeR @ Wb^T) * (degE*Wdiag), slice-major output --------
// 128x128 tile, BK=32, 4 waves of 64x64, 16x16x32 MFMA (m97 structure).
__global__ __launch_bounds__(256) void gemm_kernel(const u16* __restrict__ A,
                                                   const u16* __restrict__ B,
                                                   const float* __restrict__ degE,
                                                   const float* __restrict__ Wdiag,
                                                   u16* __restrict__ C) {
  __shared__ u16 sA[128 * 32];
  __shared__ u16 sB[128 * 32];
  const int tid  = threadIdx.x;
  const int lane = tid & 63;
  const int wave = tid >> 6;
  const int bm = blockIdx.y * 128;
  const int bn = blockIdx.x * 128;
  const int wm = (wave >> 1) * 64;
  const int wn = (wave & 1) * 64;
  const int lr = lane & 15;
  const int lk = (lane >> 4) * 8;
  const int srow = lane >> 2;        // 0..15: row within 16-row staging stripe
  const int scol = (lane & 3) * 8;   // 0/8/16/24: k-elem offset (16B)

  f32x4 acc[4][4] = {};

  for (int kt = 0; kt < D; kt += 32) {
    __syncthreads();  // previous iteration's LDS readers done
#pragma unroll
    for (int c = 0; c < 2; c++) {
      const int ar = wave * 16 + c * 64;          // wave-uniform stripe base row
      gload_lds16(A + (size_t)(bm + ar + srow) * D + kt + scol, &sA[ar * 32]);
      gload_lds16(B + (size_t)(bn + ar + srow) * D + kt + scol, &sB[ar * 32]);
    }
    __syncthreads();  // drains vmcnt: staging complete

    bf16x8 af[4], bfr[4];
#pragma unroll
    for (int i = 0; i < 4; i++) af[i]  = *(const bf16x8*)&sA[(wm + i * 16 + lr) * 32 + lk];
#pragma unroll
    for (int j = 0; j < 4; j++) bfr[j] = *(const bf16x8*)&sB[(wn + j * 16 + lr) * 32 + lk];
#pragma unroll
    for (int i = 0; i < 4; i++)
#pragma unroll
      for (int j = 0; j < 4; j++)
        acc[i][j] = __builtin_amdgcn_mfma_f32_16x16x32_bf16(af[i], bfr[j], acc[i][j], 0, 0, 0);
  }

  // C/D layout (16x16): col = lane&15, row = (lane>>4)*4 + reg
  // Output slice-major [8][MP2][64]; scale rows by degE*Wdiag. NT stores.
#pragma unroll
  for (int i = 0; i < 4; i++)
#pragma unroll
    for (int r = 0; r < 4; r++) {
      int row = bm + wm + i * 16 + (lane >> 4) * 4 + r;
      if (row < NE) {
        float se = degE[row] * Wdiag[row];
#pragma unroll
        for (int j = 0; j < 4; j++) {
          int col = bn + wn + lr + j * 16;
          int s = col >> 6, w = col & 63;
          __builtin_nontemporal_store(f2bf(acc[i][j][r] * se),
                                      C + (size_t)s * MP2 * 64 + (size_t)row * 64 + w);
        }
      }
    }
}

// ---------------- stage 2: hyperedge -> vertex ---------------------------------------
// Xe2 slice-major [8][MP2][64] (3.21 MB slice, pinned via bid&7). Wave = 8 groups x 8
// lanes, degree-SORTED ranks, cached coalesced idx loads, 16-DEEP gather windows.
// out written with NT stores -> no write-allocate eviction of the pinned slice.
__global__ __launch_bounds__(256) void stage2_kernel(
    const u16* __restrict__ Xe2, const i32x4* __restrict__ sV_meta,
    const int* __restrict__ csr_ve, float* __restrict__ out) {
  const int wave = threadIdx.x >> 6;
  const int lane = threadIdx.x & 63;
  const int g    = lane >> 3;      // 0..7: segment slot
  const int c    = lane & 7;       // 8 lanes x 16B = 128B = 64 cols
  const int s    = blockIdx.x & 7;
  const int vg   = blockIdx.x >> 3;
  const int rank = vg * 32 + wave * 8 + g;
  const u16* base = Xe2 + (size_t)s * MP2 * 64;
  int v = 0, start = 0, cnt = 0;
  float dv = 0.f;
  if (rank < NV) {
    i32x4 m = sV_meta[rank];
    v = m.x; start = m.y; cnt = m.z; dv = __int_as_float(m.w);
  }
  float acc[8] = {};
  int j0 = 0;
  for (; j0 + 16 <= cnt; j0 += 16) {            // full windows: no guards
    int ia = csr_ve[start + j0 + c];
    int ib = csr_ve[start + j0 + 8 + c];
    u32x4 pk[16];
#pragma unroll
    for (int k = 0; k < 16; k++) {
      int e = __shfl((k < 8) ? ia : ib, (lane & ~7) | (k & 7), 64);
      pk[k] = *(const u32x4*)(base + (size_t)e * 64 + c * 8);
    }
#pragma unroll
    for (int k = 0; k < 16; k++)
#pragma unroll
      for (int q = 0; q < 4; q++) {
        u32 u = pk[k][q];
        acc[2 * q]     += __uint_as_float(u << 16);
        acc[2 * q + 1] += __uint_as_float(u & 0xffff0000u);
      }
  }
  const int rem = cnt - j0;                     // 0..15, group-uniform
  if (rem) {
    int ia = csr_ve[start + j0 + c];            // <=60B overread: lands in-ws, safe
    int ib = csr_ve[start + j0 + 8 + c];
    u32x4 pk[16];
#pragma unroll
    for (int k = 0; k < 16; k++) {
      if (k < rem) {
        int e = __shfl((k < 8) ? ia : ib, (lane & ~7) | (k & 7), 64);
        pk[k] = *(const u32x4*)(base + (size_t)e * 64 + c * 8);
      }
    }
#pragma unroll
    for (int k = 0; k < 16; k++)
      if (k < rem)
#pragma unroll
        for (int q = 0; q < 4; q++) {
          u32 u = pk[k][q];
          acc[2 * q]     += __uint_as_float(u << 16);
          acc[2 * q + 1] += __uint_as_float(u & 0xffff0000u);
        }
  }
  if (rank < NV) {
    float* orow = out + (size_t)v * D + s * 64 + c * 8;
    f32x4 o0 = { acc[0] * dv, acc[1] * dv, acc[2] * dv, acc[3] * dv };
    f32x4 o1 = { acc[4] * dv, acc[5] * dv, acc[6] * dv, acc[7] * dv };
    __builtin_nontemporal_store(o0, (f32x4*)orow);
    __builtin_nontemporal_store(o1, (f32x4*)(orow + 4));
  }
}

extern "C" void kernel_launch(void* const* d_in, const int* in_sizes, int n_in,
                              void* d_out, int out_size, void* d_ws, size_t ws_size,
                              hipStream_t stream) {
  const float* X     = (const float*)d_in[0];
  const float* W     = (const float*)d_in[1];
  const float* degE  = (const float*)d_in[2];
  const float* degV  = (const float*)d_in[3];
  const float* Wdiag = (const float*)d_in[4];
  const int*   vidx  = (const int*)d_in[5];
  const int*   eidx  = (const int*)d_in[6];
  float* out = (float*)d_out;

  // workspace carve (all 256B aligned); total ~110 MB
  char* p = (char*)d_ws;
  auto take = [&](size_t bytes) { char* r = p; p += (bytes + 255) & ~(size_t)255; return r; };
  u16* Xb     = (u16*)take((size_t)NV * D * 2);    // bf16 X, slice-major [16][NV][32]
  u16* Wb     = (u16*)take((size_t)D * D * 2);     // bf16 W, row-major
  u16* XeR    = (u16*)take((size_t)MP2 * D * 2);   // bf16 raw edge sums, row-major
  u16* Xe2    = (u16*)take((size_t)MP2 * D * 2);   // bf16 projected+scaled, slice-major [8][MP2][64]
  int* cntE   = (int*)take((size_t)NE * 4);
  int* offE   = (int*)take((size_t)NE * 4);
  int* curE   = (int*)take((size_t)NE * 4);
  int* cntV   = (int*)take((size_t)NV * 4);
  int* offV   = (int*)take((size_t)NV * 4);
  int* curV   = (int*)take((size_t)NV * 4);
  int* csr_ev = (int*)take((size_t)NNZp * 4);
  int* csr_ve = (int*)take((size_t)NNZp * 4);
  int* blkSum = (int*)take((size_t)(NBE + NBV) * 4);
  int* dhistE = (int*)take(64 * 4);
  int* dhistV = (int*)take(64 * 4);
  int* dcurE  = (int*)take(64 * 4);
  int* dcurV  = (int*)take(64 * 4);
  i32x4* sE_meta = (i32x4*)take((size_t)NE * 16);
  i32x4* sV_meta = (i32x4*)take((size_t)NV * 16);

  constexpr size_t NCONV = ((size_t)NV * D + (size_t)D * D) / 8 / 256;  // 12628 exact
  constexpr int NSEG = (NV + 255) / 256;  // 196

  zero_kernel   <<<NSEG, 256, 0, stream>>>(cntE, cntV, dhistE, dhistV);
  hist_kernel   <<<(NNZp + 255) / 256, 256, 0, stream>>>(vidx, eidx, cntE, cntV);
  scan1_kernel  <<<NBE + NBV, 256, 0, stream>>>(cntE, cntV, offE, offV, blkSum, dhistE, dhistV);
  scan2_kernel  <<<1, 256, 0, stream>>>(blkSum, dhistE, dhistV, dcurE, dcurV);
  scan3_kernel  <<<NBE + NBV, 256, 0, stream>>>(offE, offV, curE, curV, blkSum,
                                                cntE, cntV, degV, dcurE, dcurV,
                                                sE_meta, sV_meta);
  scatter_kernel<<<(NNZp + 255) / 256, 256, 0, stream>>>(vidx, eidx, curE, curV, csr_ev, csr_ve);
  convert_kernel<<<NCONV, 256, 0, stream>>>(X, W, Xb, Wb);
  stage1_kernel <<<BPS1 * 16, 256, 0, stream>>>(Xb, sE_meta, csr_ev, XeR);
  gemm_kernel   <<<dim3(D / 128, MP2 / 128), 256, 0, stream>>>(XeR, Wb, degE, Wdiag, Xe2);
  stage2_kernel <<<BPS2 * 8, 256, 0, stream>>>(Xe2, sV_meta, csr_ve, out);
}